// Round 1
// baseline (144009.595 us; speedup 1.0000x reference)
//
#include <hip/hip_runtime.h>
#include <math.h>

// GRU: B=64, S=512, I=256, H=1024, O=256
// Per step s:
//   z = sigmoid(xt@Wxz + h@Whz + bz)
//   r = sigmoid(xt@Wxr + h@Whr + br)
//   n = tanh(xt@Wxh + (r*h)@Whh + bh)
//   h = (1-z)*h + z*n
// out = h_final @ Wf + bf
//
// Round 1: correctness-first fp32 baseline. 2 kernels per step (grid-wide
// dependency between z/r and n), 1024 graph nodes + head. Measures graph
// node overhead + L2 behavior to steer the MFMA/persistent-kernel rewrite.

#define Bn 64
#define Sn 512
#define In 256
#define Hn 1024
#define On 256
#define BT 4   // batch rows per block

// Phase 1: z and r gates + abuf = r*h.
// grid = 8 j-blocks * 16 b-tiles = 128 blocks, 128 threads each.
__global__ __launch_bounds__(128) void gate_kernel(
    const float* __restrict__ x,   const float* __restrict__ Wxz,
    const float* __restrict__ Whz, const float* __restrict__ Wxr,
    const float* __restrict__ Whr, const float* __restrict__ bz,
    const float* __restrict__ br,  const float* __restrict__ h,
    float* __restrict__ zbuf, float* __restrict__ abuf, int s)
{
  const int j  = (blockIdx.x & 7) * 128 + threadIdx.x;
  const int b0 = (blockIdx.x >> 3) * BT;
  __shared__ float hs[BT][64];
  float az[BT] = {0.f, 0.f, 0.f, 0.f};
  float ar[BT] = {0.f, 0.f, 0.f, 0.f};

  // h part: K = 1024
  for (int kc = 0; kc < Hn; kc += 64) {
    int i0 = threadIdx.x, i1 = threadIdx.x + 128;
    hs[i0 >> 6][i0 & 63] = h[(b0 + (i0 >> 6)) * Hn + kc + (i0 & 63)];
    hs[i1 >> 6][i1 & 63] = h[(b0 + (i1 >> 6)) * Hn + kc + (i1 & 63)];
    __syncthreads();
#pragma unroll 8
    for (int kk = 0; kk < 64; ++kk) {
      float wz = Whz[(size_t)(kc + kk) * Hn + j];
      float wr = Whr[(size_t)(kc + kk) * Hn + j];
#pragma unroll
      for (int t = 0; t < BT; ++t) {
        az[t] = fmaf(hs[t][kk], wz, az[t]);
        ar[t] = fmaf(hs[t][kk], wr, ar[t]);
      }
    }
    __syncthreads();
  }
  // x part: K = 256 (x-projection folded in; avoids a 400MB precompute buffer)
  for (int kc = 0; kc < In; kc += 64) {
    int i0 = threadIdx.x, i1 = threadIdx.x + 128;
    hs[i0 >> 6][i0 & 63] = x[((size_t)(b0 + (i0 >> 6)) * Sn + s) * In + kc + (i0 & 63)];
    hs[i1 >> 6][i1 & 63] = x[((size_t)(b0 + (i1 >> 6)) * Sn + s) * In + kc + (i1 & 63)];
    __syncthreads();
#pragma unroll 8
    for (int kk = 0; kk < 64; ++kk) {
      float wz = Wxz[(size_t)(kc + kk) * Hn + j];
      float wr = Wxr[(size_t)(kc + kk) * Hn + j];
#pragma unroll
      for (int t = 0; t < BT; ++t) {
        az[t] = fmaf(hs[t][kk], wz, az[t]);
        ar[t] = fmaf(hs[t][kk], wr, ar[t]);
      }
    }
    __syncthreads();
  }

  const float bzj = bz[j], brj = br[j];
#pragma unroll
  for (int t = 0; t < BT; ++t) {
    int idx = (b0 + t) * Hn + j;
    float z = 1.f / (1.f + __expf(-(az[t] + bzj)));
    float r = 1.f / (1.f + __expf(-(ar[t] + brj)));
    zbuf[idx] = z;
    abuf[idx] = r * h[idx];
  }
}

// Phase 2: n = tanh(xt@Wxh + abuf@Whh + bh); h = (1-z)*h + z*n  (in place)
__global__ __launch_bounds__(128) void cand_kernel(
    const float* __restrict__ x,   const float* __restrict__ Wxh,
    const float* __restrict__ Whh, const float* __restrict__ bh,
    const float* __restrict__ zbuf, const float* __restrict__ abuf,
    float* __restrict__ h, int s)
{
  const int j  = (blockIdx.x & 7) * 128 + threadIdx.x;
  const int b0 = (blockIdx.x >> 3) * BT;
  __shared__ float as[BT][64];
  float an[BT] = {0.f, 0.f, 0.f, 0.f};

  for (int kc = 0; kc < Hn; kc += 64) {
    int i0 = threadIdx.x, i1 = threadIdx.x + 128;
    as[i0 >> 6][i0 & 63] = abuf[(b0 + (i0 >> 6)) * Hn + kc + (i0 & 63)];
    as[i1 >> 6][i1 & 63] = abuf[(b0 + (i1 >> 6)) * Hn + kc + (i1 & 63)];
    __syncthreads();
#pragma unroll 8
    for (int kk = 0; kk < 64; ++kk) {
      float wh = Whh[(size_t)(kc + kk) * Hn + j];
#pragma unroll
      for (int t = 0; t < BT; ++t) an[t] = fmaf(as[t][kk], wh, an[t]);
    }
    __syncthreads();
  }
  for (int kc = 0; kc < In; kc += 64) {
    int i0 = threadIdx.x, i1 = threadIdx.x + 128;
    as[i0 >> 6][i0 & 63] = x[((size_t)(b0 + (i0 >> 6)) * Sn + s) * In + kc + (i0 & 63)];
    as[i1 >> 6][i1 & 63] = x[((size_t)(b0 + (i1 >> 6)) * Sn + s) * In + kc + (i1 & 63)];
    __syncthreads();
#pragma unroll 8
    for (int kk = 0; kk < 64; ++kk) {
      float wh = Wxh[(size_t)(kc + kk) * Hn + j];
#pragma unroll
      for (int t = 0; t < BT; ++t) an[t] = fmaf(as[t][kk], wh, an[t]);
    }
    __syncthreads();
  }

  const float bhj = bh[j];
#pragma unroll
  for (int t = 0; t < BT; ++t) {
    int idx = (b0 + t) * Hn + j;
    float n = tanhf(an[t] + bhj);
    float z = zbuf[idx];
    h[idx] = (1.f - z) * h[idx] + z * n;   // safe: dot used abuf, not h
  }
}

// out[b][o] = sum_k h[b][k] * Wf[k][o] + bf[o]
__global__ __launch_bounds__(256) void head_kernel(
    const float* __restrict__ h, const float* __restrict__ Wf,
    const float* __restrict__ bf, float* __restrict__ out)
{
  const int b = blockIdx.x;
  const int o = threadIdx.x;
  float acc = bf[o];
  for (int k = 0; k < Hn; ++k)
    acc = fmaf(h[b * Hn + k], Wf[(size_t)k * On + o], acc);
  out[b * On + o] = acc;
}

extern "C" void kernel_launch(void* const* d_in, const int* in_sizes, int n_in,
                              void* d_out, int out_size, void* d_ws, size_t ws_size,
                              hipStream_t stream) {
  const float* x   = (const float*)d_in[0];
  const float* Wxz = (const float*)d_in[1];
  const float* Whz = (const float*)d_in[2];
  const float* Wxr = (const float*)d_in[3];
  const float* Whr = (const float*)d_in[4];
  const float* Wxh = (const float*)d_in[5];
  const float* Whh = (const float*)d_in[6];
  const float* bz  = (const float*)d_in[7];
  const float* br  = (const float*)d_in[8];
  const float* bh  = (const float*)d_in[9];
  const float* Wf  = (const float*)d_in[10];
  const float* bf  = (const float*)d_in[11];
  float* out = (float*)d_out;

  float* h    = (float*)d_ws;           // [64][1024]
  float* zbuf = h    + Bn * Hn;         // [64][1024]
  float* abuf = zbuf + Bn * Hn;         // [64][1024]

  hipMemsetAsync(h, 0, Bn * Hn * sizeof(float), stream);  // h0 = zeros

  for (int s = 0; s < Sn; ++s) {
    gate_kernel<<<128, 128, 0, stream>>>(x, Wxz, Whz, Wxr, Whr, bz, br,
                                         h, zbuf, abuf, s);
    cand_kernel<<<128, 128, 0, stream>>>(x, Wxh, Whh, bh, zbuf, abuf, h, s);
  }
  head_kernel<<<Bn, On, 0, stream>>>(h, Wf, bf, out);
}

// Round 2
// 31339.886 us; speedup vs baseline: 4.5951x; 4.5951x over previous
//
#include <hip/hip_runtime.h>
#include <math.h>

// GRU: B=64, S=512, I=256, H=1024, O=256.
// Round 2: single persistent cooperative kernel.
//   - 256 blocks (1/CU) x 256 threads (4 waves).
//   - Block (bg,c): bg = batch group (16 rows), c = column slice (16 cols each
//     of z, r, n). Its 48 weight columns (K=1280 = [Wh;Wx]) live in LDS as
//     bf16, transposed (col-major K) for ds_read_b128 B-fragments. Loaded once,
//     reused 512 steps.
//   - MFMA 16x16x32 bf16, K split 4 ways across waves, LDS reduction.
//   - h: fp32 master (recurrence math) + bf16 mirror (MFMA A operand).
//   - 2 grid barriers/step via 2-level monotonic atomic counters (agent scope).
//   - Head GEMM (h_final @ Wf + bf) fused after last barrier on blocks 0..63.

#define KP 1288   // LDS K-stride (elems): 2576 B, 16B aligned, ~2-way banks max

typedef __attribute__((ext_vector_type(8))) short bf8;
typedef __attribute__((ext_vector_type(4))) short bf4;
typedef __attribute__((ext_vector_type(4))) float f32x4;

__device__ __forceinline__ short f2b(float f) {
  unsigned u = __builtin_bit_cast(unsigned, f);
  u += 0x7fffu + ((u >> 16) & 1u);          // RNE
  return (short)(u >> 16);
}
__device__ __forceinline__ float b2f(short s) {
  unsigned u = ((unsigned)(unsigned short)s) << 16;
  return __builtin_bit_cast(float, u);
}
__device__ __forceinline__ float sigm(float x) { return 1.f / (1.f + __expf(-x)); }
__device__ __forceinline__ float tanh_(float x) {
  float t = fminf(fmaxf(x, -12.f), 12.f);
  float e = __expf(2.f * t);
  return (e - 1.f) / (e + 1.f);
}

// ---------------- preprocessing ----------------

// x fp32 [64*512*256] -> bf16
__global__ __launch_bounds__(256) void cvt_x(const float* __restrict__ in,
                                             short* __restrict__ outp) {
  int idx = blockIdx.x * 256 + threadIdx.x;        // 8192 blocks, 4 floats each
  float4 v = ((const float4*)in)[idx];
  bf4 o;
  o[0] = f2b(v.x); o[1] = f2b(v.y); o[2] = f2b(v.z); o[3] = f2b(v.w);
  ((bf4*)outp)[idx] = o;
}

// Pack Wt[g][j][k] = bf16( k<1024 ? Wh_g[k][j] : Wx_g[k-1024][j] ), k=0..1279.
// Tiled 64x64 transpose through LDS. grid = 3 gates * 16 jt * 20 kt = 960.
__global__ __launch_bounds__(256) void pack_w(
    const float* __restrict__ Whz, const float* __restrict__ Wxz,
    const float* __restrict__ Whr, const float* __restrict__ Wxr,
    const float* __restrict__ Whh, const float* __restrict__ Wxh,
    short* __restrict__ Wt) {
  int b = blockIdx.x;
  int g = b / 320, rem = b % 320;
  int jt = rem / 20, kt = rem % 20;
  int j0 = jt * 64, k0 = kt * 64;
  const float* Wh = (g == 0) ? Whz : (g == 1) ? Whr : Whh;
  const float* Wx = (g == 0) ? Wxz : (g == 1) ? Wxr : Wxh;
  __shared__ short tile[64 * 72];
  int tid = threadIdx.x;
  // load 64 k-rows x 64 j-cols, coalesced over j
  for (int p = 0; p < 16; ++p) {
    int r = p * 4 + (tid >> 6);
    int cc = tid & 63;
    int k = k0 + r;
    float v = (k < 1024) ? Wh[(size_t)k * 1024 + j0 + cc]
                         : Wx[(size_t)(k - 1024) * 1024 + j0 + cc];
    tile[r * 72 + cc] = f2b(v);
  }
  __syncthreads();
  // write transposed: j-major, k-contiguous
  int j = tid >> 2, kq = tid & 3;
  bf8 v0, v1;
#pragma unroll
  for (int i = 0; i < 8; ++i) {
    v0[i] = tile[(kq * 16 + i) * 72 + j];
    v1[i] = tile[(kq * 16 + 8 + i) * 72 + j];
  }
  short* dst = Wt + ((size_t)(g * 1024 + j0 + j)) * 1280 + k0 + kq * 16;
  *(bf8*)dst = v0;
  *((bf8*)dst + 1) = v1;
}

// ---------------- grid barrier ----------------
// ctrl layout (ints): grp[g] at 32*g (g<8); gflag[g] at 256+32*g;
// root at 512; rootflag at 544. Monotonic counters, phase = 1,2,3,...
__device__ __forceinline__ void gbar(int* ctrl, int phase) {
  __syncthreads();
  if (threadIdx.x == 0) {
    int g = blockIdx.x >> 5;
    int* grp   = ctrl + g * 32;
    int* gflag = ctrl + 256 + g * 32;
    int* root  = ctrl + 512;
    int* rflag = ctrl + 544;
    int a = __hip_atomic_fetch_add(grp, 1, __ATOMIC_ACQ_REL, __HIP_MEMORY_SCOPE_AGENT);
    if (a == phase * 32 - 1) {          // last of this group
      int r = __hip_atomic_fetch_add(root, 1, __ATOMIC_ACQ_REL, __HIP_MEMORY_SCOPE_AGENT);
      if (r == phase * 8 - 1) {         // last group overall -> release
        __hip_atomic_store(rflag, phase, __ATOMIC_RELEASE, __HIP_MEMORY_SCOPE_AGENT);
      } else {
        while (__hip_atomic_load(rflag, __ATOMIC_ACQUIRE, __HIP_MEMORY_SCOPE_AGENT) < phase)
          __builtin_amdgcn_s_sleep(2);
      }
      __hip_atomic_store(gflag, phase, __ATOMIC_RELEASE, __HIP_MEMORY_SCOPE_AGENT);
    } else {
      while (__hip_atomic_load(gflag, __ATOMIC_ACQUIRE, __HIP_MEMORY_SCOPE_AGENT) < phase)
        __builtin_amdgcn_s_sleep(2);
    }
  }
  __syncthreads();
}

// ---------------- persistent GRU kernel ----------------
__global__ __launch_bounds__(256, 1) void gru_persistent(
    const short* __restrict__ xx,   // x bf16 [64][512][256]
    const short* __restrict__ Wt,   // packed weights bf16 [3][1024][1280]
    float* __restrict__ h32,        // fp32 h master [64][1024]
    short* __restrict__ h16,        // bf16 h mirror
    short* __restrict__ ab,         // bf16 abuf = r*h [64][1024]
    int* __restrict__ ctrl,
    const float* __restrict__ bz, const float* __restrict__ br,
    const float* __restrict__ bh,
    const float* __restrict__ Wf, const float* __restrict__ bfv,
    float* __restrict__ out) {
  extern __shared__ short lds[];                 // 48*KP weights + scratch
  float* sp = (float*)(lds + 48 * KP);           // 2048 floats: [2][4][64][4]

  const int tid = threadIdx.x;
  const int w = tid >> 6, lane = tid & 63;
  const int row16 = lane & 15, quad = lane >> 4;
  const int c = blockIdx.x & 63, bg = blockIdx.x >> 6;
  const int j0 = c * 16, bg0 = bg * 16;
  const int bA = bg0 + row16;                    // batch row this lane loads

  const float bzv = bz[j0 + row16];
  const float brv = br[j0 + row16];
  const float bhv = bh[j0 + row16];

  // ---- load this block's 48 weight columns into LDS (transposed, bf16) ----
  for (int ch = tid; ch < 48 * 160; ch += 256) {
    int lc = ch / 160, c8 = ch % 160;
    int g = lc >> 4, j = j0 + (lc & 15);
    bf8 v = *(const bf8*)(Wt + ((size_t)(g * 1024 + j)) * 1280 + c8 * 8);
    *(bf8*)(lds + lc * KP + c8 * 8) = v;
  }
  __syncthreads();

  float zreg[4] = {0.f, 0.f, 0.f, 0.f};          // wave0 carries z across phases
  int phase = 0;

  for (int s = 0; s < 512; ++s) {
    const short* xrow = xx + (bA * 512 + s) * 256 - 1024;  // +k valid for k>=1024

    // ---------- phase 1: z, r ----------
    f32x4 az = {0.f, 0.f, 0.f, 0.f}, ar = {0.f, 0.f, 0.f, 0.f};
#pragma unroll
    for (int kt = 0; kt < 10; ++kt) {
      int k = w * 320 + kt * 32 + quad * 8;
      const short* ap = (k < 1024) ? (h16 + bA * 1024 + k) : (xrow + k);
      bf8 a = *(const bf8*)ap;
      bf8 wzf = *(const bf8*)(lds + row16 * KP + k);
      bf8 wrf = *(const bf8*)(lds + (16 + row16) * KP + k);
      az = __builtin_amdgcn_mfma_f32_16x16x32_bf16(a, wzf, az, 0, 0, 0);
      ar = __builtin_amdgcn_mfma_f32_16x16x32_bf16(a, wrf, ar, 0, 0, 0);
    }
#pragma unroll
    for (int i = 0; i < 4; ++i) {
      sp[w * 256 + lane * 4 + i] = az[i];
      sp[1024 + w * 256 + lane * 4 + i] = ar[i];
    }
    __syncthreads();
    if (w < 2) {
      int base = w * 1024;
      float acc[4] = {0.f, 0.f, 0.f, 0.f};
#pragma unroll
      for (int ww = 0; ww < 4; ++ww)
#pragma unroll
        for (int i = 0; i < 4; ++i) acc[i] += sp[base + ww * 256 + lane * 4 + i];
      if (w == 0) {
#pragma unroll
        for (int i = 0; i < 4; ++i) zreg[i] = sigm(acc[i] + bzv);
      } else {
#pragma unroll
        for (int i = 0; i < 4; ++i) {
          float r = sigm(acc[i] + brv);
          int row = bg0 + quad * 4 + i, col = j0 + row16;
          float hv = b2f(h16[row * 1024 + col]);
          ab[row * 1024 + col] = f2b(r * hv);
        }
      }
    }
    gbar(ctrl, ++phase);   // abuf (r*h) globally visible

    // ---------- phase 2: n, h update ----------
    f32x4 an = {0.f, 0.f, 0.f, 0.f};
#pragma unroll
    for (int kt = 0; kt < 10; ++kt) {
      int k = w * 320 + kt * 32 + quad * 8;
      const short* ap = (k < 1024) ? (ab + bA * 1024 + k) : (xrow + k);
      bf8 a = *(const bf8*)ap;
      bf8 wnf = *(const bf8*)(lds + (32 + row16) * KP + k);
      an = __builtin_amdgcn_mfma_f32_16x16x32_bf16(a, wnf, an, 0, 0, 0);
    }
#pragma unroll
    for (int i = 0; i < 4; ++i) sp[w * 256 + lane * 4 + i] = an[i];
    __syncthreads();
    if (w == 0) {
      float acc[4] = {0.f, 0.f, 0.f, 0.f};
#pragma unroll
      for (int ww = 0; ww < 4; ++ww)
#pragma unroll
        for (int i = 0; i < 4; ++i) acc[i] += sp[ww * 256 + lane * 4 + i];
#pragma unroll
      for (int i = 0; i < 4; ++i) {
        float n = tanh_(acc[i] + bhv);
        int row = bg0 + quad * 4 + i, col = j0 + row16;
        int idx = row * 1024 + col;
        float ho = h32[idx];
        float hn = fmaf(zreg[i], n - ho, ho);    // (1-z)h + z*n
        h32[idx] = hn;
        h16[idx] = f2b(hn);
      }
    }
    gbar(ctrl, ++phase);   // h globally visible
  }

  // ---------- head: out = h @ Wf + bf  (fp32, blocks 0..63) ----------
  if (blockIdx.x < 64) {
    int bt = blockIdx.x >> 4, ot = blockIdx.x & 15;
    int row = bt * 16 + (tid >> 4);
    int col = ot * 16 + (tid & 15);
    float acc = bfv[col];
#pragma unroll 8
    for (int k = 0; k < 1024; ++k)
      acc = fmaf(h32[row * 1024 + k], Wf[(size_t)k * 256 + col], acc);
    out[row * 256 + col] = acc;
  }
}

// ---------------- host ----------------
extern "C" void kernel_launch(void* const* d_in, const int* in_sizes, int n_in,
                              void* d_out, int out_size, void* d_ws, size_t ws_size,
                              hipStream_t stream) {
  const float* x   = (const float*)d_in[0];
  const float* Wxz = (const float*)d_in[1];
  const float* Whz = (const float*)d_in[2];
  const float* Wxr = (const float*)d_in[3];
  const float* Whr = (const float*)d_in[4];
  const float* Wxh = (const float*)d_in[5];
  const float* Whh = (const float*)d_in[6];
  const float* bz  = (const float*)d_in[7];
  const float* br  = (const float*)d_in[8];
  const float* bh  = (const float*)d_in[9];
  const float* Wf  = (const float*)d_in[10];
  const float* bfp = (const float*)d_in[11];
  float* out = (float*)d_out;

  char* ws = (char*)d_ws;
  float* h32 = (float*)(ws + 0);            // 256 KB
  short* h16 = (short*)(ws + 262144);       // 128 KB
  int*   ctrl= (int*)  (ws + 393216);       // 4 KB
  short* ab  = (short*)(ws + 397312);       // 128 KB
  short* xx  = (short*)(ws + 528384);       // 16 MB
  short* Wt  = (short*)(ws + 17305600);     // 7.86 MB   (total ~24 MB)

  hipMemsetAsync(d_ws, 0, 397312, stream);  // h32 + h16 + ctrl = zeros

  cvt_x<<<8192, 256, 0, stream>>>(x, xx);
  pack_w<<<960, 256, 0, stream>>>(Whz, Wxz, Whr, Wxr, Whh, Wxh, Wt);

  const int smem = 48 * KP * 2 + 2048 * 4;  // 131840 B
  hipFuncSetAttribute((const void*)gru_persistent,
                      hipFuncAttributeMaxDynamicSharedMemorySize, smem);
  void* args[] = {&xx, &Wt, &h32, &h16, &ab, &ctrl,
                  (void*)&bz, (void*)&br, (void*)&bh, (void*)&Wf, (void*)&bfp, &out};
  hipLaunchCooperativeKernel((const void*)gru_persistent, dim3(256), dim3(256),
                             args, smem, stream);
}

// Round 3
// 9194.102 us; speedup vs baseline: 15.6633x; 3.4087x over previous
//
#include <hip/hip_runtime.h>
#include <math.h>

// GRU: B=64, S=512, I=256, H=1024, O=256.
// Round 3: persistent cooperative kernel, latency-optimized barriers.
//   - 64 blocks x 256 threads. Block c owns cols [16c,16c+16) of all 3 gates:
//     48 weight columns (K=1280=[Wh;Wx]) bf16 in LDS (123.6 KB), loaded once.
//   - Wave w owns batch rows [16w,16w+16): full-K MFMA per wave -> z,r,n and
//     h (fp32) for its 16x16 tile live in registers. No cross-wave reduction.
//   - Exchange (ab=r*h, h16) via sc0sc1 write-through stores (visible at LLC
//     cross-XCD); readers do ONE acquire fence per barrier (buffer_inv),
//     poll uses RELAXED system-scope loads (no invalidation storm).
//   - x-projection MFMAs (k>=1024) computed between barrier arrive and wait.

#define KP 1288   // LDS K-stride (elems): 2576 B, 16B aligned

typedef __attribute__((ext_vector_type(8))) short bf8;
typedef __attribute__((ext_vector_type(4))) short bf4;
typedef __attribute__((ext_vector_type(4))) float f32x4;

__device__ __forceinline__ short f2b(float f) {
  unsigned u = __builtin_bit_cast(unsigned, f);
  u += 0x7fffu + ((u >> 16) & 1u);          // RNE
  return (short)(u >> 16);
}
__device__ __forceinline__ float sigm(float x) { return 1.f / (1.f + __expf(-x)); }
__device__ __forceinline__ float tanh_(float x) {
  float t = fminf(fmaxf(x, -12.f), 12.f);
  float e = __expf(2.f * t);
  return (e - 1.f) / (e + 1.f);
}

// write-through stores: land at LLC (coherence point), bypass per-XCD L2
__device__ __forceinline__ void st_b16_llc(short* p, short v) {
  int vv = (int)(unsigned short)v;
  asm volatile("global_store_short %0, %1, off sc0 sc1" :: "v"(p), "v"(vv) : "memory");
}
__device__ __forceinline__ void st_f32_llc(float* p, float v) {
  asm volatile("global_store_dword %0, %1, off sc0 sc1" :: "v"(p), "v"(v) : "memory");
}

// ---------------- preprocessing ----------------

__global__ __launch_bounds__(256) void cvt_x(const float* __restrict__ in,
                                             short* __restrict__ outp) {
  int idx = blockIdx.x * 256 + threadIdx.x;        // 8192 blocks, 4 floats each
  float4 v = ((const float4*)in)[idx];
  bf4 o;
  o[0] = f2b(v.x); o[1] = f2b(v.y); o[2] = f2b(v.z); o[3] = f2b(v.w);
  ((bf4*)outp)[idx] = o;
}

// Wt[g][j][k] = bf16( k<1024 ? Wh_g[k][j] : Wx_g[k-1024][j] ), k=0..1279.
__global__ __launch_bounds__(256) void pack_w(
    const float* __restrict__ Whz, const float* __restrict__ Wxz,
    const float* __restrict__ Whr, const float* __restrict__ Wxr,
    const float* __restrict__ Whh, const float* __restrict__ Wxh,
    short* __restrict__ Wt) {
  int b = blockIdx.x;
  int g = b / 320, rem = b % 320;
  int jt = rem / 20, kt = rem % 20;
  int j0 = jt * 64, k0 = kt * 64;
  const float* Wh = (g == 0) ? Whz : (g == 1) ? Whr : Whh;
  const float* Wx = (g == 0) ? Wxz : (g == 1) ? Wxr : Wxh;
  __shared__ short tile[64 * 72];
  int tid = threadIdx.x;
  for (int p = 0; p < 16; ++p) {
    int r = p * 4 + (tid >> 6);
    int cc = tid & 63;
    int k = k0 + r;
    float v = (k < 1024) ? Wh[(size_t)k * 1024 + j0 + cc]
                         : Wx[(size_t)(k - 1024) * 1024 + j0 + cc];
    tile[r * 72 + cc] = f2b(v);
  }
  __syncthreads();
  int j = tid >> 2, kq = tid & 3;
  bf8 v0, v1;
#pragma unroll
  for (int i = 0; i < 8; ++i) {
    v0[i] = tile[(kq * 16 + i) * 72 + j];
    v1[i] = tile[(kq * 16 + 8 + i) * 72 + j];
  }
  short* dst = Wt + ((size_t)(g * 1024 + j0 + j)) * 1280 + k0 + kq * 16;
  *(bf8*)dst = v0;
  *((bf8*)dst + 1) = v1;
}

// ---------------- barrier (monotonic, two-level 8x8) ----------------
// ctrl: group counters at 32*g (g<8), root at 256.
__device__ __forceinline__ void arrive(int* ctrl, int p) {
  int g = blockIdx.x & 7;
  int a = __hip_atomic_fetch_add(ctrl + g * 32, 1, __ATOMIC_RELAXED,
                                 __HIP_MEMORY_SCOPE_SYSTEM);
  if (a == p * 8 - 1)
    __hip_atomic_fetch_add(ctrl + 256, 1, __ATOMIC_RELAXED,
                           __HIP_MEMORY_SCOPE_SYSTEM);
}
__device__ __forceinline__ void waitp(int* ctrl, int p) {
  while (__hip_atomic_load(ctrl + 256, __ATOMIC_RELAXED,
                           __HIP_MEMORY_SCOPE_SYSTEM) < p * 8)
    __builtin_amdgcn_s_sleep(2);
}
__device__ __forceinline__ void acq() {
  __builtin_amdgcn_fence(__ATOMIC_ACQUIRE, "agent");   // buffer_inv, once
}

#define MFMA __builtin_amdgcn_mfma_f32_16x16x32_bf16

// ---------------- persistent GRU kernel ----------------
__global__ __launch_bounds__(256, 1) void gru_persistent(
    const short* __restrict__ xx,   // x bf16 [64][512][256]
    const short* __restrict__ Wt,   // packed weights bf16 [3][1024][1280]
    float* __restrict__ h32,        // fp32 h final [64][1024] (written s=511)
    short* __restrict__ h16,        // bf16 h (exchange)
    short* __restrict__ ab,         // bf16 r*h (exchange)
    int* __restrict__ ctrl,
    const float* __restrict__ bz, const float* __restrict__ br,
    const float* __restrict__ bh,
    const float* __restrict__ Wf, const float* __restrict__ bfv,
    float* __restrict__ out) {
  extern __shared__ short lds[];                 // 48*KP weights

  const int tid = threadIdx.x;
  const int w = tid >> 6, lane = tid & 63;
  const int row16 = lane & 15, quad = lane >> 4;
  const int j0 = blockIdx.x * 16;
  const int bg0 = w * 16;
  const int bA = bg0 + row16;                    // batch row for A-loads

  const float bzv = bz[j0 + row16];
  const float brv = br[j0 + row16];
  const float bhv = bh[j0 + row16];

  // weights -> LDS (48 cols x 1280, transposed, bf16)
  for (int ch = tid; ch < 48 * 160; ch += 256) {
    int lc = ch / 160, c8 = ch % 160;
    int g = lc >> 4, j = j0 + (lc & 15);
    *(bf8*)(lds + lc * KP + c8 * 8) =
        *(const bf8*)(Wt + ((size_t)(g * 1024 + j)) * 1280 + c8 * 8);
  }
  __syncthreads();

  const short* wzp = lds + row16 * KP;
  const short* wrp = lds + (16 + row16) * KP;
  const short* wnp = lds + (32 + row16) * KP;
  const int ko = quad * 8;

  float hreg[4] = {0.f, 0.f, 0.f, 0.f};          // fp32 h, lives in regs
  float zreg[4];
  int p = 0;

  for (int s = 0; s < 512; ++s) {
    const short* xrow = xx + (bA * 512 + s) * 256 - 1024;  // +k valid k>=1024

    // ---------- phase 1: z, r ----------
    f32x4 az0 = {0.f,0.f,0.f,0.f}, az1 = {0.f,0.f,0.f,0.f};
    f32x4 ar0 = {0.f,0.f,0.f,0.f}, ar1 = {0.f,0.f,0.f,0.f};
    // x-part (independent of barrier)
#pragma unroll
    for (int kt = 32; kt < 40; ++kt) {
      int k = kt * 32 + ko;
      bf8 a = *(const bf8*)(xrow + k);
      az0 = MFMA(a, *(const bf8*)(wzp + k), az0, 0, 0, 0);
      ar0 = MFMA(a, *(const bf8*)(wrp + k), ar0, 0, 0, 0);
    }
    if (s > 0) { if (tid == 0) waitp(ctrl, p); }
    __syncthreads();
    if (s > 0) acq();
    // h-part, 2 chains per gate
#pragma unroll 4
    for (int kt = 0; kt < 32; kt += 2) {
      int k0 = kt * 32 + ko, k1 = k0 + 32;
      bf8 a0 = *(const bf8*)(h16 + bA * 1024 + k0);
      bf8 a1 = *(const bf8*)(h16 + bA * 1024 + k1);
      az0 = MFMA(a0, *(const bf8*)(wzp + k0), az0, 0, 0, 0);
      az1 = MFMA(a1, *(const bf8*)(wzp + k1), az1, 0, 0, 0);
      ar0 = MFMA(a0, *(const bf8*)(wrp + k0), ar0, 0, 0, 0);
      ar1 = MFMA(a1, *(const bf8*)(wrp + k1), ar1, 0, 0, 0);
    }
    f32x4 azs = az0 + az1, ars = ar0 + ar1;
#pragma unroll
    for (int i = 0; i < 4; ++i) {
      zreg[i] = sigm(azs[i] + bzv);
      float r = sigm(ars[i] + brv);
      st_b16_llc(&ab[(bg0 + quad * 4 + i) * 1024 + j0 + row16], f2b(r * hreg[i]));
    }
    __syncthreads();                             // drains sc0sc1 stores (vmcnt)
    if (tid == 0) arrive(ctrl, ++p); else ++p;

    // ---------- phase 2: n, h update ----------
    f32x4 an0 = {0.f,0.f,0.f,0.f}, an1 = {0.f,0.f,0.f,0.f};
#pragma unroll
    for (int kt = 32; kt < 40; ++kt) {
      int k = kt * 32 + ko;
      bf8 a = *(const bf8*)(xrow + k);
      an0 = MFMA(a, *(const bf8*)(wnp + k), an0, 0, 0, 0);
    }
    if (tid == 0) waitp(ctrl, p);
    __syncthreads();
    acq();
#pragma unroll 4
    for (int kt = 0; kt < 32; kt += 2) {
      int k0 = kt * 32 + ko, k1 = k0 + 32;
      bf8 a0 = *(const bf8*)(ab + bA * 1024 + k0);
      bf8 a1 = *(const bf8*)(ab + bA * 1024 + k1);
      an0 = MFMA(a0, *(const bf8*)(wnp + k0), an0, 0, 0, 0);
      an1 = MFMA(a1, *(const bf8*)(wnp + k1), an1, 0, 0, 0);
    }
    f32x4 ans = an0 + an1;
#pragma unroll
    for (int i = 0; i < 4; ++i) {
      float n = tanh_(ans[i] + bhv);
      int idx = (bg0 + quad * 4 + i) * 1024 + j0 + row16;
      hreg[i] = fmaf(zreg[i], n - hreg[i], hreg[i]);   // (1-z)h + z*n
      st_b16_llc(&h16[idx], f2b(hreg[i]));
      if (s == 511) st_f32_llc(&h32[idx], hreg[i]);
    }
    __syncthreads();
    if (tid == 0) arrive(ctrl, ++p); else ++p;
  }

  // ---------- head: out[b][o] = sum_k h32[b][k]*Wf[k][o] + bf[o] ----------
  if (tid == 0) waitp(ctrl, p);
  __syncthreads();
  acq();
  {
    const float* hrow = h32 + blockIdx.x * 1024;
    float acc = bfv[tid];
#pragma unroll 8
    for (int k = 0; k < 1024; ++k)
      acc = fmaf(hrow[k], Wf[(size_t)k * 256 + tid], acc);
    out[blockIdx.x * 256 + tid] = acc;
  }
}

// ---------------- host ----------------
extern "C" void kernel_launch(void* const* d_in, const int* in_sizes, int n_in,
                              void* d_out, int out_size, void* d_ws, size_t ws_size,
                              hipStream_t stream) {
  const float* x   = (const float*)d_in[0];
  const float* Wxz = (const float*)d_in[1];
  const float* Whz = (const float*)d_in[2];
  const float* Wxr = (const float*)d_in[3];
  const float* Whr = (const float*)d_in[4];
  const float* Wxh = (const float*)d_in[5];
  const float* Whh = (const float*)d_in[6];
  const float* bz  = (const float*)d_in[7];
  const float* br  = (const float*)d_in[8];
  const float* bh  = (const float*)d_in[9];
  const float* Wf  = (const float*)d_in[10];
  const float* bfp = (const float*)d_in[11];
  float* out = (float*)d_out;

  char* ws = (char*)d_ws;
  float* h32 = (float*)(ws + 0);            // 256 KB
  short* h16 = (short*)(ws + 262144);       // 128 KB
  int*   ctrl= (int*)  (ws + 393216);       // 4 KB
  short* ab  = (short*)(ws + 397312);       // 128 KB
  short* xx  = (short*)(ws + 528384);       // 16 MB
  short* Wt  = (short*)(ws + 17305600);     // 7.86 MB (total ~24 MB)

  hipMemsetAsync(d_ws, 0, 397312, stream);  // h32 + h16 + ctrl = zeros

  cvt_x<<<8192, 256, 0, stream>>>(x, xx);
  pack_w<<<960, 256, 0, stream>>>(Whz, Wxz, Whr, Wxr, Whh, Wxh, Wt);

  const int smem = 48 * KP * 2;             // 123,648 B
  hipFuncSetAttribute((const void*)gru_persistent,
                      hipFuncAttributeMaxDynamicSharedMemorySize, smem);
  void* args[] = {&xx, &Wt, &h32, &h16, &ab, &ctrl,
                  (void*)&bz, (void*)&br, (void*)&bh, (void*)&Wf, (void*)&bfp, &out};
  hipLaunchCooperativeKernel((const void*)gru_persistent, dim3(64), dim3(256),
                             args, smem, stream);
}